// Round 1
// baseline (1242.997 us; speedup 1.0000x reference)
//
#include <hip/hip_runtime.h>

#define NTOK 131072
#define NEXP 8
#define NDIM 128
#define TPB  8    // 64-token tiles per block
#define TOKS_PER_TILE 64   // 4 waves x 16 tokens

typedef __bf16 bf16x8 __attribute__((ext_vector_type(8)));
typedef float f32x4 __attribute__((ext_vector_type(4)));
typedef unsigned short u16x8 __attribute__((ext_vector_type(8)));

union PackAB { u16x8 u; bf16x8 b; };

// Block: 1 expert (blockIdx.y), 512 consecutive tokens (blockIdx.x), processed
// as 8 tiles of 64 tokens. W[e]^T staged to LDS (bf16, XOR-swizzled) ONCE per
// block; the tile loop has no barriers — waves stream independently.
// MFMA operands are SWAPPED vs the classic layout: D = W^T x A^T, so the C/D
// fragment has features on rows (quad*4+r) and tokens on cols (lane&15),
// giving float4 stores and bias-as-accumulator-init.
__global__ __launch_bounds__(256, 5) void seq_experts_kernel(
    const float* __restrict__ inp,   // [N, E, D] fp32
    const float* __restrict__ W,     // [E, D, D] fp32 (d rows, f contiguous)
    const float* __restrict__ bias,  // [E, D]
    float* __restrict__ out)         // [N, E, D] fp32
{
    // W^T (f-major, d contiguous) bf16, XOR-swizzled k-blocks:
    // element (f,d) at ushort index  f*128 + (((d>>3) ^ (f&15))<<3) + (d&7)
    __shared__ unsigned short Wt[NDIM * NDIM];   // 32 KiB

    const int e    = blockIdx.y;
    const int tid  = threadIdx.x;
    const int wave = tid >> 6;
    const int lane = tid & 63;
    const int quad = lane >> 4;
    const int l16  = lane & 15;

    // ---- stage W[e]^T -> LDS (bf16, swizzled), once per block ----
    {
        const float* We = W + (size_t)e * (NDIM * NDIM);
        const int f    = tid & 127;   // consecutive f across lanes -> coalesced
        const int half = tid >> 7;    // 0/1: which 8 d-blocks
        #pragma unroll
        for (int kb = 0; kb < 8; ++kb) {
            const int KB = half * 8 + kb;          // d-block 0..15
            PackAB pk;
            #pragma unroll
            for (int j = 0; j < 8; ++j)
                pk.b[j] = (__bf16)We[(size_t)(KB * 8 + j) * NDIM + f];
            *(u16x8*)&Wt[f * NDIM + ((KB ^ (f & 15)) << 3)] = pk.u;
        }
    }
    __syncthreads();

    const float*  be         = bias + e * NDIM;
    const size_t  row_stride = (size_t)NEXP * NDIM;   // 1024 floats per token

    for (int t = 0; t < TPB; ++t) {
        // this wave's 16 tokens; lane l16 owns token n
        const int n = (blockIdx.x * TPB + t) * TOKS_PER_TILE + wave * 16 + l16;
        const float* arow = inp + (size_t)n * row_stride + e * NDIM + quad * 8;

        // ---- B-operand fragments straight from global, fp32 -> bf16 ----
        // B layout (16x16x32): lane holds B[k=quad*8+j][col=l16 (token)]
        bf16x8 afrag[4];
        #pragma unroll
        for (int ks = 0; ks < 4; ++ks) {
            float4 x = *(const float4*)(arow + ks * 32);
            float4 y = *(const float4*)(arow + ks * 32 + 4);
            PackAB pk;
            pk.b[0] = (__bf16)x.x; pk.b[1] = (__bf16)x.y;
            pk.b[2] = (__bf16)x.z; pk.b[3] = (__bf16)x.w;
            pk.b[4] = (__bf16)y.x; pk.b[5] = (__bf16)y.y;
            pk.b[6] = (__bf16)y.z; pk.b[7] = (__bf16)y.w;
            afrag[ks] = pk.b;
        }

        // ---- acc init = bias (D row = feature quad*4+r) ----
        f32x4 acc[8];
        #pragma unroll
        for (int ct = 0; ct < 8; ++ct)
            acc[ct] = *(const f32x4*)(be + ct * 16 + quad * 4);

        // ---- MFMA: 4 k-steps x 8 feature-tiles, operands swapped ----
        #pragma unroll
        for (int ks = 0; ks < 4; ++ks) {
            const int kb = ks * 4 + quad;         // d-block for this lane's W frag
            #pragma unroll
            for (int ct = 0; ct < 8; ++ct) {
                const int f = ct * 16 + l16;
                PackAB pk;
                pk.u = *(const u16x8*)&Wt[f * NDIM + ((kb ^ l16) << 3)];
                acc[ct] = __builtin_amdgcn_mfma_f32_16x16x32_bf16(
                              pk.b, afrag[ks], acc[ct], 0, 0, 0);
            }
        }

        // ---- epilogue: contiguous float4 stores (4 features per lane) ----
        float* orow = out + (size_t)n * row_stride + e * NDIM + quad * 4;
        #pragma unroll
        for (int ct = 0; ct < 8; ++ct)
            *(f32x4*)(orow + ct * 16) = acc[ct];
    }
}

extern "C" void kernel_launch(void* const* d_in, const int* in_sizes, int n_in,
                              void* d_out, int out_size, void* d_ws, size_t ws_size,
                              hipStream_t stream) {
    const float* inp  = (const float*)d_in[0];
    const float* W    = (const float*)d_in[1];
    const float* bb   = (const float*)d_in[2];
    float* out = (float*)d_out;
    dim3 grid(NTOK / (TPB * TOKS_PER_TILE), NEXP);   // (256, 8)
    seq_experts_kernel<<<grid, dim3(256), 0, stream>>>(inp, W, bb, out);
}

// Round 2
// 864.743 us; speedup vs baseline: 1.4374x; 1.4374x over previous
//
#include <hip/hip_runtime.h>

#define NTOK 131072
#define NEXP 8
#define NDIM 128
#define NWAVES 8           // 512 threads
#define TOKS_PER_TILE 128  // 8 waves x 16 tokens
#define TPB 4              // tiles per block -> 512 tokens per block

typedef __bf16 bf16x8 __attribute__((ext_vector_type(8)));
typedef float f32x4 __attribute__((ext_vector_type(4)));
typedef unsigned short u16x8 __attribute__((ext_vector_type(8)));

union PackAB { u16x8 u; bf16x8 b; };

// Block: 1 expert, 512 consecutive tokens as 4 lockstep tiles of 128.
// W[e]^T staged to LDS (bf16, XOR-swizzled) once per block.
// __syncthreads() per tile keeps all 8 waves' load/store bursts dense —
// round-1 showed barrier-free drift costs 2.5x HBM traffic (partial-line
// RMW on output + lost L3 retention on input).
// MFMA operands swapped: D rows = features (quad*4+r), cols = tokens (l16)
// -> float4 epilogue stores, bias preloaded into the accumulator.
__global__ __launch_bounds__(512, 8) void seq_experts_kernel(
    const float* __restrict__ inp,   // [N, E, D] fp32
    const float* __restrict__ W,     // [E, D, D] fp32 (d rows, f contiguous)
    const float* __restrict__ bias,  // [E, D]
    float* __restrict__ out)         // [N, E, D] fp32
{
    // W^T (f-major, d contiguous) bf16, XOR-swizzled k-blocks:
    // element (f,d) at ushort index  f*128 + (((d>>3) ^ (f&15))<<3) + (d&7)
    __shared__ unsigned short Wt[NDIM * NDIM];   // 32 KiB

    const int bid  = blockIdx.x;
    const int e    = bid & 7;        // expert-inner: concurrent blocks cover
    const int xt   = bid >> 3;       // all 8 slices of the same token rows
    const int tid  = threadIdx.x;
    const int wave = tid >> 6;
    const int lane = tid & 63;
    const int quad = lane >> 4;
    const int l16  = lane & 15;

    // ---- stage W[e]^T -> LDS (bf16, swizzled), once per block ----
    {
        const float* We = W + (size_t)e * (NDIM * NDIM);
        const int f   = tid & 127;   // consecutive f across lanes -> coalesced
        const int grp = tid >> 7;    // 0..3: which 4 d-blocks
        #pragma unroll
        for (int kb = 0; kb < 4; ++kb) {
            const int KB = grp * 4 + kb;           // d-block 0..15
            PackAB pk;
            #pragma unroll
            for (int j = 0; j < 8; ++j)
                pk.b[j] = (__bf16)We[(size_t)(KB * 8 + j) * NDIM + f];
            *(u16x8*)&Wt[f * NDIM + ((KB ^ (f & 15)) << 3)] = pk.u;
        }
    }
    __syncthreads();

    const float*  be         = bias + e * NDIM;
    const size_t  row_stride = (size_t)NEXP * NDIM;   // 1024 floats per token

    for (int t = 0; t < TPB; ++t) {
        // this wave's 16 tokens; lane l16 owns token n
        const int n = (xt * TPB + t) * TOKS_PER_TILE + wave * 16 + l16;
        const float* arow = inp + (size_t)n * row_stride + e * NDIM + quad * 8;

        // ---- B-operand fragments straight from global, fp32 -> bf16 ----
        // B layout (16x16x32): lane holds B[k=quad*8+j][col=l16 (token)]
        bf16x8 afrag[4];
        #pragma unroll
        for (int ks = 0; ks < 4; ++ks) {
            float4 x = *(const float4*)(arow + ks * 32);
            float4 y = *(const float4*)(arow + ks * 32 + 4);
            PackAB pk;
            pk.b[0] = (__bf16)x.x; pk.b[1] = (__bf16)x.y;
            pk.b[2] = (__bf16)x.z; pk.b[3] = (__bf16)x.w;
            pk.b[4] = (__bf16)y.x; pk.b[5] = (__bf16)y.y;
            pk.b[6] = (__bf16)y.z; pk.b[7] = (__bf16)y.w;
            afrag[ks] = pk.b;
        }

        // ---- acc init = bias (D row = feature quad*4+r) ----
        f32x4 acc[8];
        #pragma unroll
        for (int ct = 0; ct < 8; ++ct)
            acc[ct] = *(const f32x4*)(be + ct * 16 + quad * 4);

        // ---- MFMA: 4 k-steps x 8 feature-tiles, operands swapped ----
        #pragma unroll
        for (int ks = 0; ks < 4; ++ks) {
            const int kb = ks * 4 + quad;         // d-block for this lane's W frag
            #pragma unroll
            for (int ct = 0; ct < 8; ++ct) {
                const int f = ct * 16 + l16;
                PackAB pk;
                pk.u = *(const u16x8*)&Wt[f * NDIM + ((kb ^ l16) << 3)];
                acc[ct] = __builtin_amdgcn_mfma_f32_16x16x32_bf16(
                              pk.b, afrag[ks], acc[ct], 0, 0, 0);
            }
        }

        // ---- epilogue: contiguous float4 stores (4 features per lane) ----
        float* orow = out + (size_t)n * row_stride + e * NDIM + quad * 4;
        #pragma unroll
        for (int ct = 0; ct < 8; ++ct)
            *(f32x4*)(orow + ct * 16) = acc[ct];

        // lockstep: drain this tile's stores before anyone starts the next
        if (t + 1 < TPB) __syncthreads();
    }
}

extern "C" void kernel_launch(void* const* d_in, const int* in_sizes, int n_in,
                              void* d_out, int out_size, void* d_ws, size_t ws_size,
                              hipStream_t stream) {
    const float* inp  = (const float*)d_in[0];
    const float* W    = (const float*)d_in[1];
    const float* bb   = (const float*)d_in[2];
    float* out = (float*)d_out;
    const int nblocks = (NTOK / (TPB * TOKS_PER_TILE)) * NEXP;   // 256*8 = 2048
    seq_experts_kernel<<<dim3(nblocks), dim3(512), 0, stream>>>(inp, W, bb, out);
}